// Round 1
// baseline (1220.143 us; speedup 1.0000x reference)
//
#include <hip/hip_runtime.h>

// SuperpixelPooling: per-(batch, superpixel) mean of 64-dim feature vectors.
// feat[8,512,512,64] f32, labels[8,512,512] i32 in [0,256) -> out[8,256,64] f32.
//
// Strategy: LDS-privatized scatter-reduce. ssum[256][64] = exactly 64 KiB/block,
// lane = channel so ds_add_f32 addresses are lane-contiguous (2-way bank alias,
// free on gfx950). Counts via a separate cheap histogram kernel (8 MB read).
// d_out doubles as the global sum accumulator (zeroed first; harness poisons it).

#define NBATCH 8
#define NSEG 256
#define NCH 64
#define PIX_PER_BATCH (512 * 512)

#define POOL_BLOCKS_PER_BATCH 64   // 512 blocks total = 2 resident per CU (LDS-limited)
#define POOL_THREADS 512           // 8 waves/block -> 16 waves/CU
#define CNT_BLOCKS_PER_BATCH 32
#define CNT_THREADS 256

__global__ __launch_bounds__(256) void zero_kernel(float* __restrict__ out,
                                                   unsigned* __restrict__ counts) {
    int i = blockIdx.x * 256 + threadIdx.x;
    if (i < NBATCH * NSEG * NCH) out[i] = 0.0f;
    if (i < NBATCH * NSEG) counts[i] = 0u;
}

__global__ __launch_bounds__(CNT_THREADS) void count_kernel(const int* __restrict__ sp,
                                                            unsigned* __restrict__ counts) {
    __shared__ unsigned hist[NSEG];
    for (int i = threadIdx.x; i < NSEG; i += CNT_THREADS) hist[i] = 0u;
    __syncthreads();
    const int b = blockIdx.x / CNT_BLOCKS_PER_BATCH;
    const int chunk = blockIdx.x % CNT_BLOCKS_PER_BATCH;
    const int per = PIX_PER_BATCH / CNT_BLOCKS_PER_BATCH;  // 8192
    const int4* p4 = (const int4*)(sp + (size_t)b * PIX_PER_BATCH + (size_t)chunk * per);
    const int n4 = per / 4;  // 2048
    for (int i = threadIdx.x; i < n4; i += CNT_THREADS) {
        int4 v = p4[i];
        atomicAdd(&hist[v.x], 1u);
        atomicAdd(&hist[v.y], 1u);
        atomicAdd(&hist[v.z], 1u);
        atomicAdd(&hist[v.w], 1u);
    }
    __syncthreads();
    for (int i = threadIdx.x; i < NSEG; i += CNT_THREADS) {
        unsigned h = hist[i];
        if (h) atomicAdd(&counts[b * NSEG + i], h);
    }
}

__global__ __launch_bounds__(POOL_THREADS) void pool_kernel(const float* __restrict__ feat,
                                                            const int* __restrict__ sp,
                                                            float* __restrict__ out) {
    __shared__ float ssum[NSEG * NCH];  // 65536 B exactly
    for (int i = threadIdx.x; i < NSEG * NCH; i += POOL_THREADS) ssum[i] = 0.0f;
    __syncthreads();

    const int lane = threadIdx.x & 63;
    const int wave = threadIdx.x >> 6;  // 0..7
    const int b = blockIdx.x / POOL_BLOCKS_PER_BATCH;
    const int chunk = blockIdx.x % POOL_BLOCKS_PER_BATCH;
    const int perBlock = PIX_PER_BATCH / POOL_BLOCKS_PER_BATCH;   // 4096
    const int perWave = perBlock / (POOL_THREADS / 64);           // 512

    const size_t pixBase = (size_t)b * PIX_PER_BATCH + (size_t)chunk * perBlock
                         + (size_t)wave * perWave;
    const int* lp = sp + pixBase;
    const float* fp = feat + pixBase * NCH + lane;

    // Per iteration: 256 B coalesced feature row (lane=channel), broadcast label,
    // one ds_add_f32 (bank = lane%32 -> free 2-way alias). Unroll for 16
    // outstanding loads; atomics have no read-dependency so the loop pipelines.
#pragma unroll 8
    for (int i = 0; i < perWave; ++i) {
        const int lab = lp[i];
        const float f = fp[(size_t)i * NCH];
        atomicAdd(&ssum[lab * NCH + lane], f);
    }
    __syncthreads();

    float* ob = out + (size_t)b * NSEG * NCH;
    for (int i = threadIdx.x; i < NSEG * NCH; i += POOL_THREADS) {
        atomicAdd(&ob[i], ssum[i]);
    }
}

__global__ __launch_bounds__(256) void finalize_kernel(float* __restrict__ out,
                                                       const unsigned* __restrict__ counts) {
    int i = blockIdx.x * 256 + threadIdx.x;
    if (i >= NBATCH * NSEG * NCH) return;
    unsigned c = counts[i >> 6];
    out[i] = out[i] / (float)(c > 1u ? c : 1u);
}

extern "C" void kernel_launch(void* const* d_in, const int* in_sizes, int n_in,
                              void* d_out, int out_size, void* d_ws, size_t ws_size,
                              hipStream_t stream) {
    const float* feat = (const float*)d_in[0];
    const int* sp = (const int*)d_in[1];
    float* out = (float*)d_out;
    unsigned* counts = (unsigned*)d_ws;  // 2048 * 4 B

    zero_kernel<<<(NBATCH * NSEG * NCH + 255) / 256, 256, 0, stream>>>(out, counts);
    count_kernel<<<NBATCH * CNT_BLOCKS_PER_BATCH, CNT_THREADS, 0, stream>>>(sp, counts);
    pool_kernel<<<NBATCH * POOL_BLOCKS_PER_BATCH, POOL_THREADS, 0, stream>>>(feat, sp, out);
    finalize_kernel<<<(NBATCH * NSEG * NCH + 255) / 256, 256, 0, stream>>>(out, counts);
}

// Round 2
// 1155.151 us; speedup vs baseline: 1.0563x; 1.0563x over previous
//
#include <hip/hip_runtime.h>

// SuperpixelPooling: per-(batch, superpixel) mean of 64-dim feature vectors.
// feat[8,512,512,64] f32, labels[8,512,512] i32 in [0,256) -> out[8,256,64] f32.
//
// Round-2 design: counting-sort the pixels into per-segment index lists
// (one global atomic per PIXEL), then a gather kernel where each block owns
// one (batch,segment) and accumulates in registers — zero atomics in the
// hot loop. Round-1 evidence: wave64 ds_add_f32 costs ~200 cyc on gfx950
// (per-lane serialized LDS atomic) — never do per-element LDS atomics.

#define NBATCH 8
#define NSEG 256                    // superpixels per batch
#define NSEGT (NBATCH * NSEG)       // 2048 global segments
#define NCH 64
#define PPB (512 * 512)             // 262144 pixels per batch (2^18)
#define NPIX (NBATCH * PPB)         // 2097152
#define STRIDE 2048                 // idx slots per segment (mean fill ~1024)

// ---------------- fast path (needs ws >= 8 KB + 16 MB) ----------------

__global__ __launch_bounds__(256) void init_kernel(float* __restrict__ out,
                                                   unsigned* __restrict__ cursor) {
    int i = blockIdx.x * 256 + threadIdx.x;
    if (i < NSEGT * NCH) out[i] = 0.0f;
    if (i < NSEGT) cursor[i] = 0u;
}

__global__ __launch_bounds__(256) void scatter_kernel(const int* __restrict__ sp,
                                                      const float* __restrict__ feat,
                                                      unsigned* __restrict__ cursor,
                                                      unsigned* __restrict__ idx,
                                                      float* __restrict__ out) {
    int t = blockIdx.x * 256 + threadIdx.x;     // pixel id, grid sized exactly
    int lab = sp[t];
    int seg = ((t >> 18) << 8) + lab;           // batch*256 + label
    unsigned pos = atomicAdd(&cursor[seg], 1u); // LLC atomic, 2048 hot counters
    if (pos < STRIDE) {
        idx[(size_t)seg * STRIDE + pos] = (unsigned)t;
    } else {
        // statistically unreachable (mean 1024, stride 2048); keep exact anyway
        const float* fr = feat + (size_t)t * NCH;
        float* orow = out + (size_t)seg * NCH;
        for (int c = 0; c < NCH; ++c) atomicAdd(&orow[c], fr[c]);
    }
}

__global__ __launch_bounds__(256) void gather_kernel(const float* __restrict__ feat,
                                                     const unsigned* __restrict__ idx,
                                                     const unsigned* __restrict__ cursor,
                                                     float* __restrict__ out) {
    __shared__ float part[4][NCH];
    const int seg = blockIdx.x;                 // one block owns one segment
    const int lane = threadIdx.x & 63;          // lane = channel
    const int wave = threadIdx.x >> 6;          // 4 waves/block
    const unsigned cnt = cursor[seg];
    const unsigned n = cnt < STRIDE ? cnt : STRIDE;
    const unsigned* lst = idx + (size_t)seg * STRIDE;

    float acc = 0.0f;
    // Per iteration: one uniform idx load (L1-resident line) + one coalesced
    // 256 B feature-row load + one v_add_f32. unroll 8 -> 8 loads in flight.
#pragma unroll 8
    for (unsigned i = (unsigned)wave; i < n; i += 4) {
        unsigned pix = lst[i];
        acc += feat[(size_t)pix * NCH + lane];
    }
    part[wave][lane] = acc;
    __syncthreads();
    if (wave == 0) {
        float s = part[0][lane] + part[1][lane] + part[2][lane] + part[3][lane];
        float prev = out[(size_t)seg * NCH + lane];  // zero + rare overflow adds
        float c = (float)(cnt > 0u ? cnt : 1u);
        out[(size_t)seg * NCH + lane] = (s + prev) / c;
    }
}

// ---------------- fallback path (tiny ws): correct, not fast ----------------

__global__ __launch_bounds__(256) void fb_init(float* __restrict__ out,
                                               unsigned* __restrict__ cnts) {
    int i = blockIdx.x * 256 + threadIdx.x;
    if (i < NSEGT * NCH) out[i] = 0.0f;
    if (i < NSEGT) cnts[i] = 0u;
}

__global__ __launch_bounds__(256) void fb_scatter(const int* __restrict__ sp,
                                                  const float* __restrict__ feat,
                                                  float* __restrict__ out,
                                                  unsigned* __restrict__ cnts) {
    long long t = (long long)blockIdx.x * 256 + threadIdx.x;  // over NPIX*NCH
    int pix = (int)(t >> 6);
    int ch = (int)(t & 63);
    int lab = sp[pix];
    int seg = ((pix >> 18) << 8) + lab;
    atomicAdd(&out[(size_t)seg * NCH + ch], feat[t]);
    if (ch == 0) atomicAdd(&cnts[seg], 1u);
}

__global__ __launch_bounds__(256) void fb_final(float* __restrict__ out,
                                                const unsigned* __restrict__ cnts) {
    int i = blockIdx.x * 256 + threadIdx.x;
    if (i >= NSEGT * NCH) return;
    unsigned c = cnts[i >> 6];
    out[i] = out[i] / (float)(c > 1u ? c : 1u);
}

extern "C" void kernel_launch(void* const* d_in, const int* in_sizes, int n_in,
                              void* d_out, int out_size, void* d_ws, size_t ws_size,
                              hipStream_t stream) {
    const float* feat = (const float*)d_in[0];
    const int* sp = (const int*)d_in[1];
    float* out = (float*)d_out;

    const size_t need = sizeof(unsigned) * ((size_t)NSEGT + (size_t)NSEGT * STRIDE);
    if (ws_size >= need) {
        unsigned* cursor = (unsigned*)d_ws;
        unsigned* idx = cursor + NSEGT;
        init_kernel<<<(NSEGT * NCH + 255) / 256, 256, 0, stream>>>(out, cursor);
        scatter_kernel<<<NPIX / 256, 256, 0, stream>>>(sp, feat, cursor, idx, out);
        gather_kernel<<<NSEGT, 256, 0, stream>>>(feat, idx, cursor, out);
    } else {
        unsigned* cnts = (unsigned*)d_ws;  // 8 KB
        fb_init<<<(NSEGT * NCH + 255) / 256, 256, 0, stream>>>(out, cnts);
        fb_scatter<<<(int)(((long long)NPIX * NCH) / 256), 256, 0, stream>>>(sp, feat, out, cnts);
        fb_final<<<(NSEGT * NCH + 255) / 256, 256, 0, stream>>>(out, cnts);
    }
}

// Round 3
// 751.098 us; speedup vs baseline: 1.6245x; 1.5379x over previous
//
#include <hip/hip_runtime.h>

// SuperpixelPooling: per-(batch, superpixel) mean of 64-dim feature vectors.
// feat[8,512,512,64] f32, labels[8,512,512] i32 in [0,256) -> out[8,256,64] f32.
//
// Round-3 design: ZERO atomics. Each block owns G=2 (batch,segment) output
// rows, scans the batch's label map with int4 loads + __ballot, and for each
// matching pixel the whole wave gather-loads the 256 B feature row
// (lane = channel) and accumulates in registers. Counts = sum of ballot
// popcounts. Labels are L2-resident (1 MB/batch); features are read exactly
// once (512 MB HBM). One kernel, no workspace, no init.
//
// Evidence trail: r1 per-element LDS atomics ~200 cyc/wave64 (pool 691 us,
// VALUBusy 0.8%); r2 global returning atomics ~60 cyc/same-line (scatter
// 465 us at 1.9% HBM). Atomics were the bottleneck both times.

#define NBATCH 8
#define NSEG 256
#define NCH 64
#define PPB (512 * 512)        // 262144 pixels per batch
#define GSEG 2                 // segments owned per block
#define NWAVE 8                // 512 threads
#define PIX_PER_WAVE (PPB / NWAVE)          // 32768
#define ITERS (PIX_PER_WAVE / (64 * 4))     // 128 int4-iterations per wave

__global__ __launch_bounds__(512, 8) void pool_kernel(const float* __restrict__ feat,
                                                      const int* __restrict__ sp,
                                                      float* __restrict__ out) {
    __shared__ float part[NWAVE][GSEG][NCH];   // 4 KB
    __shared__ unsigned scnt[NWAVE][GSEG];

    const int b = blockIdx.x >> 7;             // 1024 blocks: batch = idx/128
    const int sgrp = blockIdx.x & 127;         // segment pair
    const int seg0 = sgrp * 2;
    const int seg1 = seg0 + 1;
    const int lane = threadIdx.x & 63;
    const int wave = threadIdx.x >> 6;

    const int4* lp4 = (const int4*)(sp + (size_t)b * PPB + (size_t)wave * PIX_PER_WAVE);
    const float* fb = feat + (size_t)b * PPB * NCH + lane;  // + pixel*64 per row

    float acc0 = 0.0f, acc1 = 0.0f;
    unsigned c0 = 0u, c1 = 0u;

    int4 cur = lp4[lane];                      // prefetch chunk 0
    for (int i = 0; i < ITERS; ++i) {
        // prefetch next chunk before the branchy ballot processing
        const int ni = (i + 1 < ITERS) ? (i + 1) : i;
        int4 nxt = lp4[ni * 64 + lane];
        const int base = wave * PIX_PER_WAVE + i * 256;  // batch-local pixel base

        // process 4 label components; pixel(bit j, comp c) = base + j*4 + c
#define PROC(LV, C)                                                          \
        {                                                                    \
            unsigned long long m0 = __ballot((LV) == seg0);                  \
            unsigned long long m1 = __ballot((LV) == seg1);                  \
            c0 += (unsigned)__builtin_popcountll(m0);                        \
            c1 += (unsigned)__builtin_popcountll(m1);                        \
            while (m0) {                                                     \
                int j = __builtin_ctzll(m0); m0 &= m0 - 1;                   \
                acc0 += fb[(size_t)(base + j * 4 + (C)) * NCH];              \
            }                                                                \
            while (m1) {                                                     \
                int j = __builtin_ctzll(m1); m1 &= m1 - 1;                   \
                acc1 += fb[(size_t)(base + j * 4 + (C)) * NCH];              \
            }                                                                \
        }
        PROC(cur.x, 0)
        PROC(cur.y, 1)
        PROC(cur.z, 2)
        PROC(cur.w, 3)
#undef PROC
        cur = nxt;
    }

    part[wave][0][lane] = acc0;
    part[wave][1][lane] = acc1;
    if (lane == 0) { scnt[wave][0] = c0; scnt[wave][1] = c1; }
    __syncthreads();

    if (threadIdx.x < GSEG * NCH) {            // 128 threads: g = tid/64
        const int g = threadIdx.x >> 6;
        const int l = threadIdx.x & 63;
        float s = 0.0f;
        unsigned cn = 0u;
#pragma unroll
        for (int w = 0; w < NWAVE; ++w) {
            s += part[w][g][l];
            cn += scnt[w][g];
        }
        const size_t orow = (size_t)b * NSEG + (size_t)(seg0 + g);
        out[orow * NCH + l] = s / (float)(cn > 0u ? cn : 1u);
    }
}

extern "C" void kernel_launch(void* const* d_in, const int* in_sizes, int n_in,
                              void* d_out, int out_size, void* d_ws, size_t ws_size,
                              hipStream_t stream) {
    const float* feat = (const float*)d_in[0];
    const int* sp = (const int*)d_in[1];
    float* out = (float*)d_out;
    (void)d_ws; (void)ws_size;

    pool_kernel<<<NBATCH * (NSEG / GSEG), 512, 0, stream>>>(feat, sp, out);
}